// Round 3
// baseline (9872.913 us; speedup 1.0000x reference)
//
#include <hip/hip_runtime.h>
#include <math.h>

// Problem constants
#define BB 8
#define CC 2048
#define DD 64
#define LL 3
#define HH 4
#define DHH 16

// ---------------- exact GELU via A&S 7.1.26 erf (|err| < 1.5e-7) ----------------
__device__ __forceinline__ float gelu_f(float x) {
    float z  = 0.70710678118654752f * x;
    float az = fabsf(z);
    float t  = __builtin_amdgcn_rcpf(fmaf(0.3275911f, az, 1.0f));
    float p  = t * fmaf(t, fmaf(t, fmaf(t, fmaf(t, 1.061405429f, -1.453152027f),
                                        1.421413741f), -0.284496736f), 0.254829592f);
    float e  = __expf(-z * z);
    float r  = p * e;                                // erfc(|z|)
    float phi = (x >= 0.0f) ? fmaf(-0.5f, r, 1.0f) : 0.5f * r;
    return x * phi;
}

__device__ __forceinline__ float wave_sum64(float v) {
    #pragma unroll
    for (int off = 32; off; off >>= 1) v += __shfl_xor(v, off, 64);
    return v;
}

// ---------------- binding encoder: h = role * gelu(log1p(max(x,0)) * filler_w) ----------------
__global__ __launch_bounds__(256) void k_binding(const float* __restrict__ x,
                                                 const float* __restrict__ role,
                                                 const float* __restrict__ fw,
                                                 float* __restrict__ h) {
    int idx = blockIdx.x * 256 + threadIdx.x;        // B*C*D = 1048576
    int d  = idx & 63;
    int bc = idx >> 6;
    float xl = log1pf(fmaxf(x[bc], 0.0f));
    float f  = gelu_f(xl * fw[d]);
    h[idx] = role[(bc & (CC - 1)) * DD + d] * f;
}

// ---------------- QKV projection + qp (A=qp+b1) and kp precompute ----------------
__global__ __launch_bounds__(256) void k_qkv(const float* __restrict__ h,
                                             const float* __restrict__ qw, const float* __restrict__ qb,
                                             const float* __restrict__ kw, const float* __restrict__ kb,
                                             const float* __restrict__ vw, const float* __restrict__ vb,
                                             const float* __restrict__ w1, const float* __restrict__ b1,
                                             float* __restrict__ Q, float* __restrict__ K,
                                             float* __restrict__ V, float* __restrict__ A,
                                             float* __restrict__ KP) {
    __shared__ float hrow[4][64];
    __shared__ float qrow[4][64];
    __shared__ float krow[4][64];
    int r  = threadIdx.x >> 6;
    int j  = threadIdx.x & 63;
    int bc = blockIdx.x * 4 + r;                     // 0..16383
    hrow[r][j] = h[(size_t)bc * 64 + j];
    __syncthreads();
    float aq = qb[j], ak = kb[j], av = vb[j];
    const float* hr = hrow[r];
    #pragma unroll
    for (int i = 0; i < 64; ++i) {
        float hv = hr[i];
        aq = fmaf(hv, qw[j * 64 + i], aq);
        ak = fmaf(hv, kw[j * 64 + i], ak);
        av = fmaf(hv, vw[j * 64 + i], av);
    }
    int head = j >> 4, dh = j & 15;
    int b = bc >> 11, c = bc & (CC - 1);
    size_t o = ((size_t)(b * HH + head) * CC + c) * DHH + dh;
    Q[o] = aq; K[o] = ak; V[o] = av;
    qrow[r][j] = aq; krow[r][j] = ak;
    __syncthreads();
    float aA = b1[dh], akp = 0.0f;
    #pragma unroll
    for (int i = 0; i < 16; ++i) {
        aA  = fmaf(qrow[r][head * 16 + i], w1[dh * 48 + i],      aA);
        akp = fmaf(krow[r][head * 16 + i], w1[dh * 48 + 16 + i], akp);
    }
    A[o] = aA; KP[o] = akp;
}

// ---------------- attention with MLP scores, key-split partials ----------------
// grid: qc(8) x bh(32) x ks(4) = 1024 blocks, 256 threads (1 query/thread).
// j-loop FULLY unrolled: 256 uses of p[] in one basic block -> p register-resident
// (round-2's unroll-4 let the compiler rematerialize p from LDS: VGPR=56 but 2.4x
// the ideal instruction stream). kp read per-j as wave-uniform ds_read_b32 broadcast.
__global__ __launch_bounds__(256, 4) void k_attn(const float* __restrict__ Q, const float* __restrict__ K,
                                                 const float* __restrict__ V, const float* __restrict__ A,
                                                 const float* __restrict__ KP,
                                                 const float* __restrict__ w1g, const float* __restrict__ w2g,
                                                 float* __restrict__ PACC, float* __restrict__ PS) {
    __shared__ __attribute__((aligned(16))) float kt[64][16];
    __shared__ __attribute__((aligned(16))) float vt[64][16];
    __shared__ __attribute__((aligned(16))) float kpt[64][16];

    int tid = threadIdx.x;
    int qc = blockIdx.x & 7;
    int bh = (blockIdx.x >> 3) & 31;
    int ks = blockIdx.x >> 8;

    size_t base = (size_t)bh * (CC * DHH);
    int cq = qc * 256 + tid;

    float qv[16], Aq[16];
    {
        const float4* q4 = (const float4*)(Q + base + (size_t)cq * 16);
        const float4* a4 = (const float4*)(A + base + (size_t)cq * 16);
        #pragma unroll
        for (int i = 0; i < 4; ++i) {
            float4 a = q4[i], b = a4[i];
            qv[4*i] = a.x; qv[4*i+1] = a.y; qv[4*i+2] = a.z; qv[4*i+3] = a.w;
            Aq[4*i] = b.x; Aq[4*i+1] = b.y; Aq[4*i+2] = b.z; Aq[4*i+3] = b.w;
        }
    }
    float acc[16];
    #pragma unroll
    for (int i = 0; i < 16; ++i) acc[i] = 0.0f;
    float ssum = 0.0f;

    const float* wq = w1g + 32;                      // row j: wq[j*48 + i], wave-uniform

    int t_beg = ks * 512;
    #pragma unroll 1
    for (int t0 = t_beg; t0 < t_beg + 512; t0 += 64) {
        __syncthreads();                              // protect LDS from prior iter readers
        ((float4*)kt)[tid]  = ((const float4*)(K  + base + (size_t)t0 * 16))[tid];
        ((float4*)vt)[tid]  = ((const float4*)(V  + base + (size_t)t0 * 16))[tid];
        ((float4*)kpt)[tid] = ((const float4*)(KP + base + (size_t)t0 * 16))[tid];
        __syncthreads();

        #pragma unroll 1
        for (int kk = 0; kk < 64; ++kk) {
            // this key's row -> registers (wave-uniform LDS broadcast reads)
            float p[16];
            {
                const float4* kr4 = (const float4*)kt[kk];
                float4 k0 = kr4[0], k1 = kr4[1], k2 = kr4[2], k3 = kr4[3];
                p[0]  = qv[0]  * k0.x; p[1]  = qv[1]  * k0.y;
                p[2]  = qv[2]  * k0.z; p[3]  = qv[3]  * k0.w;
                p[4]  = qv[4]  * k1.x; p[5]  = qv[5]  * k1.y;
                p[6]  = qv[6]  * k1.z; p[7]  = qv[7]  * k1.w;
                p[8]  = qv[8]  * k2.x; p[9]  = qv[9]  * k2.y;
                p[10] = qv[10] * k2.z; p[11] = qv[11] * k2.w;
                p[12] = qv[12] * k3.x; p[13] = qv[13] * k3.y;
                p[14] = qv[14] * k3.z; p[15] = qv[15] * k3.w;
            }
            float s = 0.0f;
            #pragma unroll
            for (int j = 0; j < 16; ++j) {            // FULL unroll: p stays in VGPRs
                float r = Aq[j] + kpt[kk][j];         // wave-uniform b32 broadcast
                #pragma unroll
                for (int i = 0; i < 16; ++i)
                    r = fmaf(wq[j * 48 + i], p[i], r);   // SGPR weight operand
                s = fmaf(w2g[j], gelu_f(r), s);
            }
            // scores bounded (|s| < ~8): max-free online softmax is safe in fp32
            float e = __expf(s * 0.25f);              // fold 1/sqrt(16)
            ssum += e;
            const float4* vr4 = (const float4*)vt[kk];
            #pragma unroll
            for (int i = 0; i < 4; ++i) {
                float4 v = vr4[i];
                acc[4*i]   = fmaf(e, v.x, acc[4*i]);
                acc[4*i+1] = fmaf(e, v.y, acc[4*i+1]);
                acc[4*i+2] = fmaf(e, v.z, acc[4*i+2]);
                acc[4*i+3] = fmaf(e, v.w, acc[4*i+3]);
            }
        }
    }

    float* pa = PACC + ((size_t)(ks * 32 + bh) * CC + cq) * 16;
    #pragma unroll
    for (int i = 0; i < 4; ++i) {
        float4 o;
        o.x = acc[4*i]; o.y = acc[4*i+1]; o.z = acc[4*i+2]; o.w = acc[4*i+3];
        ((float4*)pa)[i] = o;
    }
    PS[(size_t)(ks * 32 + bh) * CC + cq] = ssum;
}

// ---------------- combine key-split partials -> attn [B,C,D] ----------------
__global__ __launch_bounds__(256) void k_attn_combine(const float* __restrict__ PACC,
                                                      const float* __restrict__ PS,
                                                      float* __restrict__ AT) {
    int idx = blockIdx.x * 256 + threadIdx.x;        // 65536 queries
    int bh = idx >> 11, cq = idx & (CC - 1);
    float acc[16];
    #pragma unroll
    for (int i = 0; i < 16; ++i) acc[i] = 0.0f;
    float ssum = 0.0f;
    #pragma unroll
    for (int s = 0; s < 4; ++s) {
        const float4* pa = (const float4*)(PACC + ((size_t)(s * 32 + bh) * CC + cq) * 16);
        ssum += PS[(size_t)(s * 32 + bh) * CC + cq];
        #pragma unroll
        for (int i = 0; i < 4; ++i) {
            float4 v = pa[i];
            acc[4*i] += v.x; acc[4*i+1] += v.y; acc[4*i+2] += v.z; acc[4*i+3] += v.w;
        }
    }
    float inv = 1.0f / ssum;
    int b = bh >> 2, hh = bh & 3;
    float* dst = AT + ((size_t)(b * CC + cq)) * DD + hh * 16;
    #pragma unroll
    for (int i = 0; i < 4; ++i) {
        float4 o;
        o.x = acc[4*i]*inv; o.y = acc[4*i+1]*inv; o.z = acc[4*i+2]*inv; o.w = acc[4*i+3]*inv;
        ((float4*)dst)[i] = o;
    }
}

// ---------------- out-proj + residual + LN1 (4 rows per 256-thread block) ----------------
__global__ __launch_bounds__(256) void k_oproj_ln(const float* __restrict__ AT,
                                                  const float* __restrict__ ow, const float* __restrict__ ob,
                                                  const float* __restrict__ g, const float* __restrict__ be,
                                                  float* __restrict__ h) {
    int r  = threadIdx.x >> 6;
    int j  = threadIdx.x & 63;
    int bc = blockIdx.x * 4 + r;
    __shared__ float ar[4][64];
    ar[r][j] = AT[(size_t)bc * 64 + j];
    __syncthreads();
    float o = ob[j];
    #pragma unroll
    for (int i = 0; i < 64; ++i) o = fmaf(ar[r][i], ow[j * 64 + i], o);
    float t = h[(size_t)bc * 64 + j] + o;
    float m  = wave_sum64(t) * (1.0f / 64.0f);
    float dv = t - m;
    float vv = wave_sum64(dv * dv) * (1.0f / 64.0f);
    float rr = __builtin_amdgcn_rsqf(vv + 1e-5f);
    h[(size_t)bc * 64 + j] = fmaf(dv * rr, g[j], be[j]);
}

// ---------------- FFN (64->256 gelu ->64) + residual + LN2 ----------------
__global__ __launch_bounds__(256) void k_ffn_ln(const float* __restrict__ f1w, const float* __restrict__ f1b,
                                                const float* __restrict__ f2w, const float* __restrict__ f2b,
                                                const float* __restrict__ g, const float* __restrict__ be,
                                                float* __restrict__ h) {
    int bc = blockIdx.x;
    int t  = threadIdx.x;
    __shared__ float hr[64];
    __shared__ float u[256];
    __shared__ float parts[4][64];
    if (t < 64) hr[t] = h[(size_t)bc * 64 + t];
    __syncthreads();
    float a = f1b[t];
    #pragma unroll
    for (int i = 0; i < 64; ++i) a = fmaf(hr[i], f1w[t * 64 + i], a);
    u[t] = gelu_f(a);
    __syncthreads();
    int j = t & 63, part = t >> 6;
    float p = 0.0f;
    #pragma unroll
    for (int i = 0; i < 64; ++i) p = fmaf(u[part * 64 + i], f2w[j * 256 + part * 64 + i], p);
    parts[part][j] = p;
    __syncthreads();
    if (t < 64) {
        float o = f2b[t] + parts[0][t] + parts[1][t] + parts[2][t] + parts[3][t];
        float x = hr[t] + o;
        float m  = wave_sum64(x) * (1.0f / 64.0f);
        float dv = x - m;
        float vv = wave_sum64(dv * dv) * (1.0f / 64.0f);
        float r  = __builtin_amdgcn_rsqf(vv + 1e-5f);
        h[(size_t)bc * 64 + t] = fmaf(dv * r, g[t], be[t]);
    }
}

// ---------------- task-query readout ----------------
__global__ __launch_bounds__(256) void k_readout(const float* __restrict__ h,
                                                 const float* __restrict__ tq,
                                                 const float* __restrict__ hw, const float* __restrict__ hb,
                                                 float* __restrict__ out) {
    int b = blockIdx.x;
    int t = threadIdx.x;
    __shared__ float ebuf[2048];
    __shared__ float tqs[64];
    __shared__ float sred[256];
    __shared__ float red[4][64];
    if (t < 64) tqs[t] = tq[t];
    __syncthreads();
    float ss = 0.0f;
    for (int c = t; c < CC; c += 256) {
        const float* hrow = h + ((size_t)b * CC + c) * 64;
        float s = 0.0f;
        #pragma unroll
        for (int d = 0; d < 64; ++d) s = fmaf(hrow[d], tqs[d], s);
        float e = __expf(s * 0.125f);                 // scores ~ +-0.1: max-free safe
        ebuf[c] = e; ss += e;
    }
    sred[t] = ss;
    __syncthreads();
    for (int o = 128; o; o >>= 1) {
        if (t < o) sred[t] += sred[t + o];
        __syncthreads();
    }
    float inv = 1.0f / sred[0];
    int d = t & 63, ch = t >> 6;
    float p = 0.0f;
    for (int c = ch * 512; c < ch * 512 + 512; ++c)
        p = fmaf(ebuf[c], h[((size_t)b * CC + c) * 64 + d], p);
    red[ch][d] = p;
    __syncthreads();
    if (t < 64) red[0][t] = (red[0][t] + red[1][t] + red[2][t] + red[3][t]) * inv;
    __syncthreads();
    if (t < 10) {
        float o = hb[t];
        #pragma unroll
        for (int d2 = 0; d2 < 64; ++d2) o = fmaf(red[0][d2], hw[t * 64 + d2], o);
        out[b * 10 + t] = o;
    }
}

extern "C" void kernel_launch(void* const* d_in, const int* in_sizes, int n_in,
                              void* d_out, int out_size, void* d_ws, size_t ws_size,
                              hipStream_t stream) {
    (void)in_sizes; (void)n_in; (void)out_size; (void)ws_size;
    const float* x    = (const float*)d_in[0];
    const float* role = (const float*)d_in[1];
    const float* fw   = (const float*)d_in[2];
    const float* qw   = (const float*)d_in[3];
    const float* qb   = (const float*)d_in[4];
    const float* kw   = (const float*)d_in[5];
    const float* kb   = (const float*)d_in[6];
    const float* vw   = (const float*)d_in[7];
    const float* vb   = (const float*)d_in[8];
    const float* w1   = (const float*)d_in[9];
    const float* b1   = (const float*)d_in[10];
    const float* w2   = (const float*)d_in[11];
    // d_in[12] = b2: softmax-shift-invariant, dropped
    const float* ow   = (const float*)d_in[13];
    const float* ob   = (const float*)d_in[14];
    const float* g1   = (const float*)d_in[15];
    const float* be1  = (const float*)d_in[16];
    const float* f1w  = (const float*)d_in[17];
    const float* f1b  = (const float*)d_in[18];
    const float* f2w  = (const float*)d_in[19];
    const float* f2b  = (const float*)d_in[20];
    const float* g2   = (const float*)d_in[21];
    const float* be2  = (const float*)d_in[22];
    const float* tq   = (const float*)d_in[23];
    const float* hw   = (const float*)d_in[24];
    const float* hb   = (const float*)d_in[25];

    float* ws   = (float*)d_ws;
    const size_t M = 1048576;                        // B*C*D
    float* H    = ws;
    float* Q    = ws + 1 * M;
    float* K    = ws + 2 * M;
    float* V    = ws + 3 * M;
    float* Abuf = ws + 4 * M;
    float* KP   = ws + 5 * M;
    float* AT   = ws + 6 * M;
    float* PACC = ws + 7 * M;                        // 4*32*2048*16 = 4M floats
    float* PS   = ws + 11 * M + 262144;              // 4*32*2048

    k_binding<<<4096, 256, 0, stream>>>(x, role, fw, H);
    for (int l = 0; l < LL; ++l) {
        k_qkv<<<4096, 256, 0, stream>>>(H, qw + l * 4096, qb + l * 64, kw + l * 4096, kb + l * 64,
                                        vw + l * 4096, vb + l * 64, w1 + l * 768, b1 + l * 16,
                                        Q, K, V, Abuf, KP);
        k_attn<<<1024, 256, 0, stream>>>(Q, K, V, Abuf, KP, w1 + l * 768, w2 + l * 16, PACC, PS);
        k_attn_combine<<<256, 256, 0, stream>>>(PACC, PS, AT);
        k_oproj_ln<<<4096, 256, 0, stream>>>(AT, ow + l * 4096, ob + l * 64, g1 + l * 64, be1 + l * 64, H);
        k_ffn_ln<<<16384, 256, 0, stream>>>(f1w + l * 16384, f1b + l * 256, f2w + l * 16384,
                                            f2b + l * 64, g2 + l * 64, be2 + l * 64, H);
    }
    k_readout<<<8, 256, 0, stream>>>(H, tq, hw, hb, (float*)d_out);
}

// Round 4
// 5001.221 us; speedup vs baseline: 1.9741x; 1.9741x over previous
//
#include <hip/hip_runtime.h>
#include <math.h>

// Problem constants
#define BB 8
#define CC 2048
#define DD 64
#define LL 3
#define HH 4
#define DHH 16
#define KPAD 40   // halves per LDS row: 32 keys + 8 pad (80B = 16B-aligned, bank-friendly)

typedef _Float16 half8 __attribute__((ext_vector_type(8)));
typedef float f32x4 __attribute__((ext_vector_type(4)));

// ---------------- exact GELU via A&S 7.1.26 erf (|err| < 1.5e-7) ----------------
__device__ __forceinline__ float gelu_f(float x) {
    float z  = 0.70710678118654752f * x;
    float az = fabsf(z);
    float t  = __builtin_amdgcn_rcpf(fmaf(0.3275911f, az, 1.0f));
    float p  = t * fmaf(t, fmaf(t, fmaf(t, fmaf(t, 1.061405429f, -1.453152027f),
                                        1.421413741f), -0.284496736f), 0.254829592f);
    float e  = __expf(-z * z);
    float r  = p * e;                                // erfc(|z|)
    float phi = (x >= 0.0f) ? fmaf(-0.5f, r, 1.0f) : 0.5f * r;
    return x * phi;
}

__device__ __forceinline__ float wave_sum64(float v) {
    #pragma unroll
    for (int off = 32; off; off >>= 1) v += __shfl_xor(v, off, 64);
    return v;
}

// ---------------- binding encoder ----------------
__global__ __launch_bounds__(256) void k_binding(const float* __restrict__ x,
                                                 const float* __restrict__ role,
                                                 const float* __restrict__ fw,
                                                 float* __restrict__ h) {
    int idx = blockIdx.x * 256 + threadIdx.x;        // B*C*D = 1048576
    int d  = idx & 63;
    int bc = idx >> 6;
    float xl = log1pf(fmaxf(x[bc], 0.0f));
    float f  = gelu_f(xl * fw[d]);
    h[idx] = role[(bc & (CC - 1)) * DD + d] * f;
}

// ---------------- QKV projection + Aq (=qp+b1) precompute ----------------
__global__ __launch_bounds__(256) void k_qkv(const float* __restrict__ h,
                                             const float* __restrict__ qw, const float* __restrict__ qb,
                                             const float* __restrict__ kw, const float* __restrict__ kb,
                                             const float* __restrict__ vw, const float* __restrict__ vb,
                                             const float* __restrict__ w1, const float* __restrict__ b1,
                                             float* __restrict__ Q, float* __restrict__ K,
                                             float* __restrict__ V, float* __restrict__ A) {
    __shared__ float hrow[4][64];
    __shared__ float qrow[4][64];
    int r  = threadIdx.x >> 6;
    int j  = threadIdx.x & 63;
    int bc = blockIdx.x * 4 + r;                     // 0..16383
    hrow[r][j] = h[(size_t)bc * 64 + j];
    __syncthreads();
    float aq = qb[j], ak = kb[j], av = vb[j];
    const float* hr = hrow[r];
    #pragma unroll
    for (int i = 0; i < 64; ++i) {
        float hv = hr[i];
        aq = fmaf(hv, qw[j * 64 + i], aq);
        ak = fmaf(hv, kw[j * 64 + i], ak);
        av = fmaf(hv, vw[j * 64 + i], av);
    }
    int head = j >> 4, dh = j & 15;
    int b = bc >> 11, c = bc & (CC - 1);
    size_t o = ((size_t)(b * HH + head) * CC + c) * DHH + dh;
    Q[o] = aq; K[o] = ak; V[o] = av;
    qrow[r][j] = aq;
    __syncthreads();
    float aA = b1[dh];
    #pragma unroll
    for (int i = 0; i < 16; ++i)
        aA = fmaf(qrow[r][head * 16 + i], w1[dh * 48 + i], aA);
    A[o] = aA;
}

// ---------------- MFMA attention with MLP scores ----------------
// grid: qtile(32, 64 queries each) x bh(32) = 1024 blocks, 4 waves/block (16 q/wave).
// res[j][k] = (W1qk∘q + W1k)_ext · K_ext via mfma_f32_16x16x32_f16 with the spare
// K-dim slot i=16 carrying Aq[j] (K row 16 = ones). Epilogue: gelu+w2 dot (rows=j ->
// per-reg fma + 2 shfl_xor), exp -> E (f16, LDS). Then E·V and E·ones MFMAs give
// numerator and softmax denominator in fp32 C — output write is lane-local.
__global__ __launch_bounds__(256, 4) void k_attn(const float* __restrict__ Q, const float* __restrict__ K,
                                                 const float* __restrict__ V, const float* __restrict__ A,
                                                 const float* __restrict__ w1g, const float* __restrict__ w2g,
                                                 float* __restrict__ AT) {
    __shared__ __attribute__((aligned(16))) _Float16 Kl[32 * KPAD];   // [key][i0..15,16=1,17..=0]
    __shared__ __attribute__((aligned(16))) _Float16 Vt[16 * KPAD];   // [d][key]
    __shared__ __attribute__((aligned(16))) _Float16 El[4][16 * KPAD];// per wave [q][key]

    int tid  = threadIdx.x;
    int lane = tid & 63;
    int w    = tid >> 6;
    int quad = lane >> 4;
    int l15  = lane & 15;
    int qt = blockIdx.x & 31;
    int bh = blockIdx.x >> 5;
    size_t base = (size_t)bh * (CC * DHH);
    int qbase = qt * 64 + w * 16;

    // one-time constant region of Kl: [16]=1.0, [17..39]=0 per key row
    for (int idx = tid; idx < 32 * 24; idx += 256) {
        int row = idx / 24, off = 16 + idx % 24;
        Kl[row * KPAD + off] = (off == 16) ? (_Float16)1.0f : (_Float16)0.0f;
    }

    // per-lane w2 for rows j = quad*4+r, with 1/sqrt(16) folded
    float w2q[4];
    #pragma unroll
    for (int r = 0; r < 4; ++r) w2q[r] = w2g[quad * 4 + r] * 0.25f;

    // Bq A-frags: m=j=lane&15, kdim=i=quad*8+jj. quads0,1: W1qk[j][i]*q[i]+W1k[j][i];
    // quad2 jj=0: Aq[j]; else 0. One per query (16), must stay register-resident.
    half8 bq[16];
    {
        int j = l15;
        #pragma unroll
        for (int q = 0; q < 16; ++q) {
            const float* qv = Q + base + (size_t)(qbase + q) * 16;
            float aqv = A[base + (size_t)(qbase + q) * 16 + j];
            half8 v;
            #pragma unroll
            for (int jj = 0; jj < 8; ++jj) {
                float val;
                if (quad < 2) {
                    int i = quad * 8 + jj;
                    val = fmaf(w1g[j * 48 + 32 + i], qv[i], w1g[j * 48 + 16 + i]);
                } else if (quad == 2 && jj == 0) {
                    val = aqv;
                } else {
                    val = 0.0f;
                }
                v[jj] = (_Float16)val;
            }
            bq[q] = v;
        }
    }

    half8 ones;
    #pragma unroll
    for (int jj = 0; jj < 8; ++jj) ones[jj] = (_Float16)1.0f;
    f32x4 Oc = {0.f, 0.f, 0.f, 0.f};
    f32x4 Dn = {0.f, 0.f, 0.f, 0.f};
    f32x4 zc = {0.f, 0.f, 0.f, 0.f};

    _Float16* Ew = El[w];

    #pragma unroll 1
    for (int t0 = 0; t0 < CC; t0 += 32) {
        __syncthreads();
        {   // stage K tile (32 keys x 16 f32 -> f16), coalesced b64 reads
            int key = tid >> 3, ip = (tid & 7) * 2;
            const float* src = K + base + (size_t)(t0 + key) * 16 + ip;
            Kl[key * KPAD + ip]     = (_Float16)src[0];
            Kl[key * KPAD + ip + 1] = (_Float16)src[1];
            // stage V transposed: Vt[d][key]
            #pragma unroll
            for (int it = 0; it < 2; ++it) {
                int idx = tid + it * 256;
                int vk = idx >> 4, d = idx & 15;
                Vt[d * KPAD + vk] = (_Float16)V[base + (size_t)(t0 + vk) * 16 + d];
            }
        }
        __syncthreads();

        #pragma unroll
        for (int sub = 0; sub < 2; ++sub) {
            // B-frag: n=key=lane&15 (local), kdim=i=quad*8+jj -> Kl row, consecutive i
            half8 bK = *(const half8*)&Kl[(sub * 16 + l15) * KPAD + quad * 8];
            #pragma unroll
            for (int q = 0; q < 16; ++q) {
                f32x4 D = __builtin_amdgcn_mfma_f32_16x16x32_f16(bq[q], bK, zc, 0, 0, 0);
                float t = 0.0f;
                #pragma unroll
                for (int r = 0; r < 4; ++r) t = fmaf(w2q[r], gelu_f(D[r]), t);
                t += __shfl_xor(t, 16, 64);           // reduce j across quads
                t += __shfl_xor(t, 32, 64);
                float e = __expf(t);                   // |t| small: max-free softmax safe
                if (lane < 16) Ew[q * KPAD + sub * 16 + lane] = (_Float16)e;
            }
        }
        // E·V numerator + E·ones denominator
        half8 aE = *(const half8*)&Ew[l15 * KPAD + quad * 8];
        half8 bV = *(const half8*)&Vt[l15 * KPAD + quad * 8];
        Oc = __builtin_amdgcn_mfma_f32_16x16x32_f16(aE, bV, Oc, 0, 0, 0);
        Dn = __builtin_amdgcn_mfma_f32_16x16x32_f16(aE, ones, Dn, 0, 0, 0);
    }

    // D layout: row(q)=quad*4+r, col(d)=lane&15; Dn replicated across cols
    int b = bh >> 2, hh = bh & 3;
    #pragma unroll
    for (int r = 0; r < 4; ++r) {
        int c = qbase + quad * 4 + r;
        AT[((size_t)(b * CC + c)) * DD + hh * 16 + l15] = Oc[r] / Dn[r];
    }
}

// ---------------- out-proj + residual + LN1 (4 rows per 256-thread block) ----------------
__global__ __launch_bounds__(256) void k_oproj_ln(const float* __restrict__ AT,
                                                  const float* __restrict__ ow, const float* __restrict__ ob,
                                                  const float* __restrict__ g, const float* __restrict__ be,
                                                  float* __restrict__ h) {
    int r  = threadIdx.x >> 6;
    int j  = threadIdx.x & 63;
    int bc = blockIdx.x * 4 + r;
    __shared__ float ar[4][64];
    ar[r][j] = AT[(size_t)bc * 64 + j];
    __syncthreads();
    float o = ob[j];
    #pragma unroll
    for (int i = 0; i < 64; ++i) o = fmaf(ar[r][i], ow[j * 64 + i], o);
    float t = h[(size_t)bc * 64 + j] + o;
    float m  = wave_sum64(t) * (1.0f / 64.0f);
    float dv = t - m;
    float vv = wave_sum64(dv * dv) * (1.0f / 64.0f);
    float rr = __builtin_amdgcn_rsqf(vv + 1e-5f);
    h[(size_t)bc * 64 + j] = fmaf(dv * rr, g[j], be[j]);
}

// ---------------- FFN (64->256 gelu ->64) + residual + LN2 ----------------
__global__ __launch_bounds__(256) void k_ffn_ln(const float* __restrict__ f1w, const float* __restrict__ f1b,
                                                const float* __restrict__ f2w, const float* __restrict__ f2b,
                                                const float* __restrict__ g, const float* __restrict__ be,
                                                float* __restrict__ h) {
    int bc = blockIdx.x;
    int t  = threadIdx.x;
    __shared__ float hr[64];
    __shared__ float u[256];
    __shared__ float parts[4][64];
    if (t < 64) hr[t] = h[(size_t)bc * 64 + t];
    __syncthreads();
    float a = f1b[t];
    #pragma unroll
    for (int i = 0; i < 64; ++i) a = fmaf(hr[i], f1w[t * 64 + i], a);
    u[t] = gelu_f(a);
    __syncthreads();
    int j = t & 63, part = t >> 6;
    float p = 0.0f;
    #pragma unroll
    for (int i = 0; i < 64; ++i) p = fmaf(u[part * 64 + i], f2w[j * 256 + part * 64 + i], p);
    parts[part][j] = p;
    __syncthreads();
    if (t < 64) {
        float o = f2b[t] + parts[0][t] + parts[1][t] + parts[2][t] + parts[3][t];
        float x = hr[t] + o;
        float m  = wave_sum64(x) * (1.0f / 64.0f);
        float dv = x - m;
        float vv = wave_sum64(dv * dv) * (1.0f / 64.0f);
        float r  = __builtin_amdgcn_rsqf(vv + 1e-5f);
        h[(size_t)bc * 64 + t] = fmaf(dv * r, g[t], be[t]);
    }
}

// ---------------- task-query readout ----------------
__global__ __launch_bounds__(256) void k_readout(const float* __restrict__ h,
                                                 const float* __restrict__ tq,
                                                 const float* __restrict__ hw, const float* __restrict__ hb,
                                                 float* __restrict__ out) {
    int b = blockIdx.x;
    int t = threadIdx.x;
    __shared__ float ebuf[2048];
    __shared__ float tqs[64];
    __shared__ float sred[256];
    __shared__ float red[4][64];
    if (t < 64) tqs[t] = tq[t];
    __syncthreads();
    float ss = 0.0f;
    for (int c = t; c < CC; c += 256) {
        const float* hrow = h + ((size_t)b * CC + c) * 64;
        float s = 0.0f;
        #pragma unroll
        for (int d = 0; d < 64; ++d) s = fmaf(hrow[d], tqs[d], s);
        float e = __expf(s * 0.125f);                 // scores ~ +-0.1: max-free safe
        ebuf[c] = e; ss += e;
    }
    sred[t] = ss;
    __syncthreads();
    for (int o = 128; o; o >>= 1) {
        if (t < o) sred[t] += sred[t + o];
        __syncthreads();
    }
    float inv = 1.0f / sred[0];
    int d = t & 63, ch = t >> 6;
    float p = 0.0f;
    for (int c = ch * 512; c < ch * 512 + 512; ++c)
        p = fmaf(ebuf[c], h[((size_t)b * CC + c) * 64 + d], p);
    red[ch][d] = p;
    __syncthreads();
    if (t < 64) red[0][t] = (red[0][t] + red[1][t] + red[2][t] + red[3][t]) * inv;
    __syncthreads();
    if (t < 10) {
        float o = hb[t];
        #pragma unroll
        for (int d2 = 0; d2 < 64; ++d2) o = fmaf(red[0][d2], hw[t * 64 + d2], o);
        out[b * 10 + t] = o;
    }
}

extern "C" void kernel_launch(void* const* d_in, const int* in_sizes, int n_in,
                              void* d_out, int out_size, void* d_ws, size_t ws_size,
                              hipStream_t stream) {
    (void)in_sizes; (void)n_in; (void)out_size; (void)ws_size;
    const float* x    = (const float*)d_in[0];
    const float* role = (const float*)d_in[1];
    const float* fw   = (const float*)d_in[2];
    const float* qw   = (const float*)d_in[3];
    const float* qb   = (const float*)d_in[4];
    const float* kw   = (const float*)d_in[5];
    const float* kb   = (const float*)d_in[6];
    const float* vw   = (const float*)d_in[7];
    const float* vb   = (const float*)d_in[8];
    const float* w1   = (const float*)d_in[9];
    const float* b1   = (const float*)d_in[10];
    const float* w2   = (const float*)d_in[11];
    // d_in[12] = b2: softmax-shift-invariant, dropped
    const float* ow   = (const float*)d_in[13];
    const float* ob   = (const float*)d_in[14];
    const float* g1   = (const float*)d_in[15];
    const float* be1  = (const float*)d_in[16];
    const float* f1w  = (const float*)d_in[17];
    const float* f1b  = (const float*)d_in[18];
    const float* f2w  = (const float*)d_in[19];
    const float* f2b  = (const float*)d_in[20];
    const float* g2   = (const float*)d_in[21];
    const float* be2  = (const float*)d_in[22];
    const float* tq   = (const float*)d_in[23];
    const float* hw   = (const float*)d_in[24];
    const float* hb   = (const float*)d_in[25];

    float* ws   = (float*)d_ws;
    const size_t M = 1048576;                        // B*C*D
    float* H    = ws;
    float* Q    = ws + 1 * M;
    float* K    = ws + 2 * M;
    float* V    = ws + 3 * M;
    float* Abuf = ws + 4 * M;
    float* AT   = ws + 5 * M;

    k_binding<<<4096, 256, 0, stream>>>(x, role, fw, H);
    for (int l = 0; l < LL; ++l) {
        k_qkv<<<4096, 256, 0, stream>>>(H, qw + l * 4096, qb + l * 64, kw + l * 4096, kb + l * 64,
                                        vw + l * 4096, vb + l * 64, w1 + l * 768, b1 + l * 16,
                                        Q, K, V, Abuf);
        k_attn<<<1024, 256, 0, stream>>>(Q, K, V, Abuf, w1 + l * 768, w2 + l * 16, AT);
        k_oproj_ln<<<4096, 256, 0, stream>>>(AT, ow + l * 4096, ob + l * 64, g1 + l * 64, be1 + l * 64, H);
        k_ffn_ln<<<16384, 256, 0, stream>>>(f1w + l * 16384, f1b + l * 256, f2w + l * 16384,
                                            f2b + l * 64, g2 + l * 64, be2 + l * 64, H);
    }
    k_readout<<<8, 256, 0, stream>>>(H, tq, hw, hb, (float*)d_out);
}

// Round 5
// 3421.493 us; speedup vs baseline: 2.8856x; 1.4617x over previous
//
#include <hip/hip_runtime.h>
#include <math.h>

// Problem constants
#define BB 8
#define CC 2048
#define DD 64
#define LL 3
#define HH 4
#define DHH 16
#define KPAD 40   // halves per LDS row: 32 keys + 8 pad (80B = 16B-aligned)

typedef _Float16 half8 __attribute__((ext_vector_type(8)));
typedef float f32x4 __attribute__((ext_vector_type(4)));

#if defined(__has_builtin)
#if __has_builtin(__builtin_amdgcn_exp2f)
#define EXP2F(x) __builtin_amdgcn_exp2f(x)
#else
#define EXP2F(x) __expf((x) * 0.693147180559945f)
#endif
#else
#define EXP2F(x) __expf((x) * 0.693147180559945f)
#endif

// ---------------- exact GELU via A&S 7.1.26 erf (residual-path kernels) ----------------
__device__ __forceinline__ float gelu_f(float x) {
    float z  = 0.70710678118654752f * x;
    float az = fabsf(z);
    float t  = __builtin_amdgcn_rcpf(fmaf(0.3275911f, az, 1.0f));
    float p  = t * fmaf(t, fmaf(t, fmaf(t, fmaf(t, 1.061405429f, -1.453152027f),
                                        1.421413741f), -0.284496736f), 0.254829592f);
    float e  = __expf(-z * z);
    float r  = p * e;                                // erfc(|z|)
    float phi = (x >= 0.0f) ? fmaf(-0.5f, r, 1.0f) : 0.5f * r;
    return x * phi;
}

// ---------------- tanh-form GELU (score path only; max |err| ~3e-4) ----------------
// x*sigmoid(1.5957691*(x+0.044715x^3)); constants pre-scaled by -log2(e) so the
// sigmoid exponential is a single raw v_exp_f32. 5 full-rate + 2 transcendental.
__device__ __forceinline__ float gelu_fast(float x) {
    float x2 = x * x;
    float f  = fmaf(-0.10294357f, x2, -2.30221895f); // -log2e*1.59577*(1+0.044715x^2)
    float e  = EXP2F(x * f);                          // exp(-1.59577(x+0.044715x^3))
    return x * __builtin_amdgcn_rcpf(1.0f + e);
}

__device__ __forceinline__ float wave_sum64(float v) {
    #pragma unroll
    for (int off = 32; off; off >>= 1) v += __shfl_xor(v, off, 64);
    return v;
}

// ---------------- binding encoder ----------------
__global__ __launch_bounds__(256) void k_binding(const float* __restrict__ x,
                                                 const float* __restrict__ role,
                                                 const float* __restrict__ fw,
                                                 float* __restrict__ h) {
    int idx = blockIdx.x * 256 + threadIdx.x;        // B*C*D = 1048576
    int d  = idx & 63;
    int bc = idx >> 6;
    float xl = log1pf(fmaxf(x[bc], 0.0f));
    float f  = gelu_f(xl * fw[d]);
    h[idx] = role[(bc & (CC - 1)) * DD + d] * f;
}

// ---------------- QKV projection + Aq (=qp+b1) precompute ----------------
__global__ __launch_bounds__(256) void k_qkv(const float* __restrict__ h,
                                             const float* __restrict__ qw, const float* __restrict__ qb,
                                             const float* __restrict__ kw, const float* __restrict__ kb,
                                             const float* __restrict__ vw, const float* __restrict__ vb,
                                             const float* __restrict__ w1, const float* __restrict__ b1,
                                             float* __restrict__ Q, float* __restrict__ K,
                                             float* __restrict__ V, float* __restrict__ A) {
    __shared__ __attribute__((aligned(16))) float hrow[4][64];
    __shared__ float qrow[4][64];
    int r  = threadIdx.x >> 6;
    int j  = threadIdx.x & 63;
    int bc = blockIdx.x * 4 + r;                     // 0..16383
    hrow[r][j] = h[(size_t)bc * 64 + j];
    __syncthreads();
    float aq = qb[j], ak = kb[j], av = vb[j];
    const float4* hr4 = (const float4*)hrow[r];
    const float4* qw4 = (const float4*)(qw + j * 64);
    const float4* kw4 = (const float4*)(kw + j * 64);
    const float4* vw4 = (const float4*)(vw + j * 64);
    #pragma unroll
    for (int i = 0; i < 16; ++i) {
        float4 hv = hr4[i];
        float4 a = qw4[i], b = kw4[i], c = vw4[i];
        aq = fmaf(hv.x, a.x, fmaf(hv.y, a.y, fmaf(hv.z, a.z, fmaf(hv.w, a.w, aq))));
        ak = fmaf(hv.x, b.x, fmaf(hv.y, b.y, fmaf(hv.z, b.z, fmaf(hv.w, b.w, ak))));
        av = fmaf(hv.x, c.x, fmaf(hv.y, c.y, fmaf(hv.z, c.z, fmaf(hv.w, c.w, av))));
    }
    int head = j >> 4, dh = j & 15;
    int b = bc >> 11, c = bc & (CC - 1);
    size_t o = ((size_t)(b * HH + head) * CC + c) * DHH + dh;
    Q[o] = aq; K[o] = ak; V[o] = av;
    qrow[r][j] = aq;
    __syncthreads();
    float aA = b1[dh];
    #pragma unroll
    for (int i = 0; i < 16; ++i)
        aA = fmaf(qrow[r][head * 16 + i], w1[dh * 48 + i], aA);
    A[o] = aA;
}

// ---------------- MFMA attention with MLP scores ----------------
// grid: qtile(32, 64 queries each) x bh(32) = 1024 blocks, 4 waves/block (16 q/wave).
// Per q: two 16-key MFMAs (kdim slot 16 carries Aq via ones-row), gelu_fast+w2 dot
// per C-reg, 2 shfl quad-reduce, cndmask t0/t1 per lane-half, ONE exp2, one lane<32
// b16 store of E. Then E·V and E·ones MFMAs accumulate numerator + denominator.
__global__ __launch_bounds__(256, 4) void k_attn(const float* __restrict__ Q, const float* __restrict__ K,
                                                 const float* __restrict__ V, const float* __restrict__ A,
                                                 const float* __restrict__ w1g, const float* __restrict__ w2g,
                                                 float* __restrict__ AT) {
    __shared__ __attribute__((aligned(16))) _Float16 Kl[32 * KPAD];   // [key][i0..15,16=1,17..=0]
    __shared__ __attribute__((aligned(16))) _Float16 Vt[16 * KPAD];   // [d][key]
    __shared__ __attribute__((aligned(16))) _Float16 El[4][16 * KPAD];// per wave [q][key]

    int tid  = threadIdx.x;
    int lane = tid & 63;
    int w    = tid >> 6;
    int quad = lane >> 4;
    int l15  = lane & 15;
    int qt = blockIdx.x & 31;
    int bh = blockIdx.x >> 5;
    size_t base = (size_t)bh * (CC * DHH);
    int qbase = qt * 64 + w * 16;

    // one-time constant region of Kl: [16]=1.0, [17..39]=0 per key row
    for (int idx = tid; idx < 32 * 24; idx += 256) {
        int row = idx / 24, off = 16 + idx % 24;
        Kl[row * KPAD + off] = (off == 16) ? (_Float16)1.0f : (_Float16)0.0f;
    }

    // per-lane w2 for rows j = quad*4+r, with 1/sqrt(16)*log2(e) folded (softmax in base 2)
    float w2q[4];
    #pragma unroll
    for (int r = 0; r < 4; ++r) w2q[r] = w2g[quad * 4 + r] * (0.25f * 1.44269504f);

    bool sel_hi = (lane & 16) != 0;                  // quads 1,3 -> sub1 value at store

    // W1k/W1qk slices are q-invariant: hoist to registers (per-lane j=l15, i=quad*8+jj)
    float wk[8], wqk[8];
    #pragma unroll
    for (int jj = 0; jj < 8; ++jj) {
        int i = (quad & 1) * 8 + jj;                 // only quads 0,1 use these
        wk[jj]  = w1g[l15 * 48 + 16 + ((quad < 2) ? quad * 8 + jj : i)];
        wqk[jj] = w1g[l15 * 48 + 32 + ((quad < 2) ? quad * 8 + jj : i)];
    }

    // Bq A-frags: m=j=lane&15, kdim=i=quad*8+jj. quads0,1: W1qk[j][i]*q[i]+W1k[j][i];
    // quad2 jj=0: Aq[j]; else 0. 16 frags (64 regs) live across the K loop.
    half8 bq[16];
    {
        int j = l15;
        #pragma unroll
        for (int q = 0; q < 16; ++q) {
            const float* qv = Q + base + (size_t)(qbase + q) * 16;
            float aqv = A[base + (size_t)(qbase + q) * 16 + j];
            half8 v;
            #pragma unroll
            for (int jj = 0; jj < 8; ++jj) {
                float val;
                if (quad < 2) {
                    val = fmaf(wqk[jj], qv[quad * 8 + jj], wk[jj]);
                } else if (quad == 2 && jj == 0) {
                    val = aqv;
                } else {
                    val = 0.0f;
                }
                v[jj] = (_Float16)val;
            }
            bq[q] = v;
        }
    }

    half8 ones;
    #pragma unroll
    for (int jj = 0; jj < 8; ++jj) ones[jj] = (_Float16)1.0f;
    f32x4 Oc = {0.f, 0.f, 0.f, 0.f};
    f32x4 Dn = {0.f, 0.f, 0.f, 0.f};
    f32x4 zc = {0.f, 0.f, 0.f, 0.f};

    _Float16* Ew = El[w];

    #pragma unroll 1
    for (int t0 = 0; t0 < CC; t0 += 32) {
        __syncthreads();
        {   // stage K tile (32 keys x 16 f32 -> f16), coalesced float2 reads
            int key = tid >> 3, ip = (tid & 7) * 2;
            float2 kv = *(const float2*)(K + base + (size_t)(t0 + key) * 16 + ip);
            Kl[key * KPAD + ip]     = (_Float16)kv.x;
            Kl[key * KPAD + ip + 1] = (_Float16)kv.y;
            // stage V transposed: Vt[d][key]
            #pragma unroll
            for (int it = 0; it < 2; ++it) {
                int idx = tid + it * 256;
                int vk = idx >> 4, d = idx & 15;
                Vt[d * KPAD + vk] = (_Float16)V[base + (size_t)(t0 + vk) * 16 + d];
            }
        }
        __syncthreads();

        half8 bK0 = *(const half8*)&Kl[l15 * KPAD + quad * 8];
        half8 bK1 = *(const half8*)&Kl[(16 + l15) * KPAD + quad * 8];

        #pragma unroll
        for (int q = 0; q < 16; ++q) {
            f32x4 D0 = __builtin_amdgcn_mfma_f32_16x16x32_f16(bq[q], bK0, zc, 0, 0, 0);
            f32x4 D1 = __builtin_amdgcn_mfma_f32_16x16x32_f16(bq[q], bK1, zc, 0, 0, 0);
            float s0 = 0.0f, s1 = 0.0f;
            #pragma unroll
            for (int r = 0; r < 4; ++r) {
                s0 = fmaf(w2q[r], gelu_fast(D0[r]), s0);
                s1 = fmaf(w2q[r], gelu_fast(D1[r]), s1);
            }
            s0 += __shfl_xor(s0, 16, 64);
            s0 += __shfl_xor(s0, 32, 64);
            s1 += __shfl_xor(s1, 16, 64);
            s1 += __shfl_xor(s1, 32, 64);
            float u = sel_hi ? s1 : s0;               // lanes 16..31 carry sub1
            float e = EXP2F(u);                       // base-2 softmax (log2e folded in w2q)
            if (lane < 32) Ew[q * KPAD + lane] = (_Float16)e;
        }
        // E·V numerator + E·ones denominator
        half8 aE = *(const half8*)&Ew[l15 * KPAD + quad * 8];
        half8 bV = *(const half8*)&Vt[l15 * KPAD + quad * 8];
        Oc = __builtin_amdgcn_mfma_f32_16x16x32_f16(aE, bV, Oc, 0, 0, 0);
        Dn = __builtin_amdgcn_mfma_f32_16x16x32_f16(aE, ones, Dn, 0, 0, 0);
    }

    // D layout: row(q)=quad*4+r, col(d)=lane&15; Dn replicated across cols
    int b = bh >> 2, hh = bh & 3;
    #pragma unroll
    for (int r = 0; r < 4; ++r) {
        int c = qbase + quad * 4 + r;
        AT[((size_t)(b * CC + c)) * DD + hh * 16 + l15] = Oc[r] / Dn[r];
    }
}

// ---------------- out-proj + residual + LN1 (4 rows per 256-thread block) ----------------
__global__ __launch_bounds__(256) void k_oproj_ln(const float* __restrict__ AT,
                                                  const float* __restrict__ ow, const float* __restrict__ ob,
                                                  const float* __restrict__ g, const float* __restrict__ be,
                                                  float* __restrict__ h) {
    int r  = threadIdx.x >> 6;
    int j  = threadIdx.x & 63;
    int bc = blockIdx.x * 4 + r;
    __shared__ __attribute__((aligned(16))) float ar[4][64];
    ar[r][j] = AT[(size_t)bc * 64 + j];
    __syncthreads();
    float o = ob[j];
    const float4* ar4 = (const float4*)ar[r];
    const float4* ow4 = (const float4*)(ow + j * 64);
    #pragma unroll
    for (int i = 0; i < 16; ++i) {
        float4 a = ar4[i], wv = ow4[i];
        o = fmaf(a.x, wv.x, fmaf(a.y, wv.y, fmaf(a.z, wv.z, fmaf(a.w, wv.w, o))));
    }
    float t = h[(size_t)bc * 64 + j] + o;
    float m  = wave_sum64(t) * (1.0f / 64.0f);
    float dv = t - m;
    float vv = wave_sum64(dv * dv) * (1.0f / 64.0f);
    float rr = __builtin_amdgcn_rsqf(vv + 1e-5f);
    h[(size_t)bc * 64 + j] = fmaf(dv * rr, g[j], be[j]);
}

// ---------------- FFN (64->256 gelu ->64) + residual + LN2 ----------------
__global__ __launch_bounds__(256) void k_ffn_ln(const float* __restrict__ f1w, const float* __restrict__ f1b,
                                                const float* __restrict__ f2w, const float* __restrict__ f2b,
                                                const float* __restrict__ g, const float* __restrict__ be,
                                                float* __restrict__ h) {
    int bc = blockIdx.x;
    int t  = threadIdx.x;
    __shared__ __attribute__((aligned(16))) float hr[64];
    __shared__ __attribute__((aligned(16))) float u[256];
    __shared__ float parts[4][64];
    if (t < 64) hr[t] = h[(size_t)bc * 64 + t];
    __syncthreads();
    float a = f1b[t];
    {
        const float4* hr4 = (const float4*)hr;
        const float4* w4  = (const float4*)(f1w + t * 64);
        #pragma unroll
        for (int i = 0; i < 16; ++i) {
            float4 hv = hr4[i], wv = w4[i];
            a = fmaf(hv.x, wv.x, fmaf(hv.y, wv.y, fmaf(hv.z, wv.z, fmaf(hv.w, wv.w, a))));
        }
    }
    u[t] = gelu_f(a);
    __syncthreads();
    int j = t & 63, part = t >> 6;
    float p = 0.0f;
    {
        const float4* u4 = (const float4*)(u + part * 64);
        const float4* w4 = (const float4*)(f2w + j * 256 + part * 64);
        #pragma unroll
        for (int i = 0; i < 16; ++i) {
            float4 uv = u4[i], wv = w4[i];
            p = fmaf(uv.x, wv.x, fmaf(uv.y, wv.y, fmaf(uv.z, wv.z, fmaf(uv.w, wv.w, p))));
        }
    }
    parts[part][j] = p;
    __syncthreads();
    if (t < 64) {
        float o = f2b[t] + parts[0][t] + parts[1][t] + parts[2][t] + parts[3][t];
        float x = hr[t] + o;
        float m  = wave_sum64(x) * (1.0f / 64.0f);
        float dv = x - m;
        float vv = wave_sum64(dv * dv) * (1.0f / 64.0f);
        float r  = __builtin_amdgcn_rsqf(vv + 1e-5f);
        h[(size_t)bc * 64 + t] = fmaf(dv * r, g[t], be[t]);
    }
}

// ---------------- task-query readout ----------------
__global__ __launch_bounds__(256) void k_readout(const float* __restrict__ h,
                                                 const float* __restrict__ tq,
                                                 const float* __restrict__ hw, const float* __restrict__ hb,
                                                 float* __restrict__ out) {
    int b = blockIdx.x;
    int t = threadIdx.x;
    __shared__ float ebuf[2048];
    __shared__ float tqs[64];
    __shared__ float sred[256];
    __shared__ float red[4][64];
    if (t < 64) tqs[t] = tq[t];
    __syncthreads();
    float ss = 0.0f;
    for (int c = t; c < CC; c += 256) {
        const float* hrow = h + ((size_t)b * CC + c) * 64;
        float s = 0.0f;
        #pragma unroll
        for (int d = 0; d < 64; ++d) s = fmaf(hrow[d], tqs[d], s);
        float e = __expf(s * 0.125f);                 // scores ~ +-0.1: max-free safe
        ebuf[c] = e; ss += e;
    }
    sred[t] = ss;
    __syncthreads();
    for (int o = 128; o; o >>= 1) {
        if (t < o) sred[t] += sred[t + o];
        __syncthreads();
    }
    float inv = 1.0f / sred[0];
    int d = t & 63, ch = t >> 6;
    float p = 0.0f;
    for (int c = ch * 512; c < ch * 512 + 512; ++c)
        p = fmaf(ebuf[c], h[((size_t)b * CC + c) * 64 + d], p);
    red[ch][d] = p;
    __syncthreads();
    if (t < 64) red[0][t] = (red[0][t] + red[1][t] + red[2][t] + red[3][t]) * inv;
    __syncthreads();
    if (t < 10) {
        float o = hb[t];
        #pragma unroll
        for (int d2 = 0; d2 < 64; ++d2) o = fmaf(red[0][d2], hw[t * 64 + d2], o);
        out[b * 10 + t] = o;
    }
}

extern "C" void kernel_launch(void* const* d_in, const int* in_sizes, int n_in,
                              void* d_out, int out_size, void* d_ws, size_t ws_size,
                              hipStream_t stream) {
    (void)in_sizes; (void)n_in; (void)out_size; (void)ws_size;
    const float* x    = (const float*)d_in[0];
    const float* role = (const float*)d_in[1];
    const float* fw   = (const float*)d_in[2];
    const float* qw   = (const float*)d_in[3];
    const float* qb   = (const float*)d_in[4];
    const float* kw   = (const float*)d_in[5];
    const float* kb   = (const float*)d_in[6];
    const float* vw   = (const float*)d_in[7];
    const float* vb   = (const float*)d_in[8];
    const float* w1   = (const float*)d_in[9];
    const float* b1   = (const float*)d_in[10];
    const float* w2   = (const float*)d_in[11];
    // d_in[12] = b2: softmax-shift-invariant, dropped
    const float* ow   = (const float*)d_in[13];
    const float* ob   = (const float*)d_in[14];
    const float* g1   = (const float*)d_in[15];
    const float* be1  = (const float*)d_in[16];
    const float* f1w  = (const float*)d_in[17];
    const float* f1b  = (const float*)d_in[18];
    const float* f2w  = (const float*)d_in[19];
    const float* f2b  = (const float*)d_in[20];
    const float* g2   = (const float*)d_in[21];
    const float* be2  = (const float*)d_in[22];
    const float* tq   = (const float*)d_in[23];
    const float* hw   = (const float*)d_in[24];
    const float* hb   = (const float*)d_in[25];

    float* ws   = (float*)d_ws;
    const size_t M = 1048576;                        // B*C*D
    float* H    = ws;
    float* Q    = ws + 1 * M;
    float* K    = ws + 2 * M;
    float* V    = ws + 3 * M;
    float* Abuf = ws + 4 * M;
    float* AT   = ws + 5 * M;

    k_binding<<<4096, 256, 0, stream>>>(x, role, fw, H);
    for (int l = 0; l < LL; ++l) {
        k_qkv<<<4096, 256, 0, stream>>>(H, qw + l * 4096, qb + l * 64, kw + l * 4096, kb + l * 64,
                                        vw + l * 4096, vb + l * 64, w1 + l * 768, b1 + l * 16,
                                        Q, K, V, Abuf);
        k_attn<<<1024, 256, 0, stream>>>(Q, K, V, Abuf, w1 + l * 768, w2 + l * 16, AT);
        k_oproj_ln<<<4096, 256, 0, stream>>>(AT, ow + l * 4096, ob + l * 64, g1 + l * 64, be1 + l * 64, H);
        k_ffn_ln<<<16384, 256, 0, stream>>>(f1w + l * 16384, f1b + l * 256, f2w + l * 16384,
                                            f2b + l * 64, g2 + l * 64, be2 + l * 64, H);
    }
    k_readout<<<8, 256, 0, stream>>>(H, tq, hw, hb, (float*)d_out);
}